// Round 2
// baseline (325.224 us; speedup 1.0000x reference)
//
#include <hip/hip_runtime.h>

// Problem constants (fixed by setup_inputs)
#define B_   4
#define C_   256
#define H_   96
#define W_   128
#define F_   9
#define G_   4
#define CG   64            // channels per group
#define NC2  32            // channel PAIRS per group
#define NO   81            // offsets
#define TH   2             // output rows per block
#define TROWS (TH + 16)    // 18 in2 rows needed (dilation=2, r=4)
#define TCOLS (W_ + 16)    // 144 cols incl halo
#define TILE_DW (TROWS * TCOLS)  // 2592 dwords per channel-pair tile

typedef _Float16 half2v __attribute__((ext_vector_type(2)));

__device__ __forceinline__ half2v u2h(unsigned u) {
    half2v h; __builtin_memcpy(&h, &u, 4); return h;
}
__device__ __forceinline__ unsigned h2u(half2v h) {
    unsigned u; __builtin_memcpy(&u, &h, 4); return u;
}
// cvt_pkrtz returns __fp16x2; bit-cast to our half2v (same 4 bytes)
__device__ __forceinline__ half2v pkrtz(float a, float b) {
    auto r = __builtin_amdgcn_cvt_pkrtz(a, b);
    half2v h; __builtin_memcpy(&h, &r, 4); return h;
}
__device__ __forceinline__ unsigned pkrtz_u(float a, float b) {
    auto r = __builtin_amdgcn_cvt_pkrtz(a, b);
    unsigned u; __builtin_memcpy(&u, &r, 4); return u;
}

#if __has_builtin(__builtin_amdgcn_fdot2)
#define FDOT2(a, b, c) __builtin_amdgcn_fdot2((a), (b), (c), false)
#else
__device__ __forceinline__ float fdot2_fb(half2v a, half2v b, float c) {
    return c + (float)a[0] * (float)b[0] + (float)a[1] * (float)b[1];
}
#define FDOT2(a, b, c) fdot2_fb((a), (b), (c))
#endif

// Pack weights [C,9,9] f32 -> [g][c2][o] as f16x2 (channel pair) in d_ws
__global__ void pack_weights_kernel(const float* __restrict__ w,
                                    unsigned* __restrict__ wp) {
    int i = blockIdx.x * blockDim.x + threadIdx.x;
    if (i >= G_ * NC2 * NO) return;
    int o  = i % NO;
    int c2 = (i / NO) % NC2;
    int g  = i / (NO * NC2);
    float a = w[(size_t)(g * CG + 2 * c2) * NO + o];
    float b = w[(size_t)(g * CG + 2 * c2 + 1) * NO + o];
    wp[i] = pkrtz_u(a, b);
}

// Stage channel-pair c2 of in2 (zero-padded halo) into LDS as packed f16x2
__device__ __forceinline__ void stage_tile(const float* __restrict__ in2g,
                                           int c2, int h0,
                                           unsigned* dst, int t) {
#pragma unroll
    for (int k = 0; k < 11; ++k) {
        int idx = k * 256 + t;
        if (k < 10 || idx < TILE_DW) {
            int row = idx / TCOLS;
            int col = idx - row * TCOLS;
            int gr = h0 - 8 + row;
            int gc = col - 8;
            float v0 = 0.f, v1 = 0.f;
            if (gr >= 0 && gr < H_ && gc >= 0 && gc < W_) {
                const float* p = in2g + ((size_t)(2 * c2) * H_ + gr) * W_ + gc;
                v0 = p[0];
                v1 = p[(size_t)H_ * W_];
            }
            dst[idx] = pkrtz_u(v0, v1);
        }
    }
}

template <bool PACKED>
__global__ __launch_bounds__(256, 3)
void wcorr_kernel(const float* __restrict__ in1, const float* __restrict__ in2,
                  const unsigned* __restrict__ wp, const float* __restrict__ wraw,
                  float* __restrict__ out) {
    __shared__ unsigned tile[2][TILE_DW];

    // XCD-aware swizzle: pair (b,g) constant per XCD run -> in2 plane stays in XCD L2
    int bid  = blockIdx.x;          // 0..767
    int xcd  = bid & 7;
    int slot = bid >> 3;            // 0..95
    int pair = xcd + 8 * (slot / 48);  // 0..15  == b*4+g
    int hblk = slot % 48;
    int b = pair >> 2, g = pair & 3;
    int h0 = hblk * TH;

    int t  = threadIdx.x;
    int ty = t >> 7;                // 0..1
    int tx = t & 127;               // 0..127

    const float* in1g = in1 + (size_t)(b * C_ + g * CG) * (H_ * W_);
    const float* in2g = in2 + (size_t)(b * C_ + g * CG) * (H_ * W_);

    float acc[NO];
#pragma unroll
    for (int o = 0; o < NO; ++o) acc[o] = 0.f;

    stage_tile(in2g, 0, h0, tile[0], t);

    const int lbase = ty * TCOLS + tx;

    for (int c2 = 0; c2 < NC2; ++c2) {
        __syncthreads();
        const unsigned* lt = tile[c2 & 1];

        // in1 channel pair for this thread's (h,w), packed to f16x2
        float a0 = in1g[((size_t)(2 * c2) * H_ + (h0 + ty)) * W_ + tx];
        float a1 = in1g[((size_t)(2 * c2 + 1) * H_ + (h0 + ty)) * W_ + tx];
        half2v a = pkrtz(a0, a1);

        const unsigned* wrow = PACKED ? (wp + ((size_t)g * NC2 + c2) * NO) : nullptr;
        const float* wr0 = wraw + (size_t)(g * CG + 2 * c2) * NO;
        const float* wr1 = wr0 + NO;

#pragma unroll
        for (int dy = 0; dy < F_; ++dy) {
#pragma unroll
            for (int dx = 0; dx < F_; ++dx) {
                const int o = dy * F_ + dx;
                unsigned uv = lt[lbase + dy * 2 * TCOLS + dx * 2]; // imm-offset ds_read
                half2v vh = u2h(uv);
                half2v wh;
                if (PACKED) {
                    wh = u2h(wrow[o]);              // uniform -> s_load
                } else {
                    wh = pkrtz(wr0[o], wr1[o]);
                }
                half2v prod = wh * a;               // v_pk_mul_f16
                acc[o] = FDOT2(prod, vh, acc[o]);   // v_dot2_f32_f16
            }
        }

        if (c2 + 1 < NC2)
            stage_tile(in2g, c2 + 1, h0, tile[(c2 + 1) & 1], t);
    }

    // out[b][g*81+o][h][w]
    size_t obase = (((size_t)pair * NO) * H_ + (h0 + ty)) * W_ + tx;
#pragma unroll
    for (int o = 0; o < NO; ++o)
        out[obase + (size_t)o * (H_ * W_)] = acc[o];
}

extern "C" void kernel_launch(void* const* d_in, const int* in_sizes, int n_in,
                              void* d_out, int out_size, void* d_ws, size_t ws_size,
                              hipStream_t stream) {
    const float* in1  = (const float*)d_in[0];
    const float* in2  = (const float*)d_in[1];
    const float* wraw = (const float*)d_in[2];
    float* out = (float*)d_out;

    const size_t wp_bytes = (size_t)G_ * NC2 * NO * 4;  // 41,472 B
    const int nblocks = B_ * G_ * (H_ / TH);            // 768 = 3 per CU

    if (ws_size >= wp_bytes) {
        unsigned* wp = (unsigned*)d_ws;
        int n = G_ * NC2 * NO;
        pack_weights_kernel<<<(n + 255) / 256, 256, 0, stream>>>(wraw, wp);
        wcorr_kernel<true><<<nblocks, 256, 0, stream>>>(in1, in2, wp, wraw, out);
    } else {
        wcorr_kernel<false><<<nblocks, 256, 0, stream>>>(in1, in2, nullptr, wraw, out);
    }
}